// Round 1
// baseline (409.966 us; speedup 1.0000x reference)
//
#include <hip/hip_runtime.h>
#include <math.h>

#define HH 128
#define WW 128
#define HW 16384
#define CIN 64
#define COUT 64
#define BATCH 8

// ---------------------------------------------------------------------------
// Kernel T: pre-transpose weights into workspace.
//   wT [kk][c][cout]  (9,64,64)  <- weight (Cout,C,3,3)
//   owT[c][k][ko]     (64,9,27)  <- offset_w (27,C,3,3)
// ---------------------------------------------------------------------------
__global__ __launch_bounds__(256) void transpose_kernel(
    const float* __restrict__ weight,
    const float* __restrict__ offset_w,
    float* __restrict__ wT,
    float* __restrict__ owT)
{
    int idx = blockIdx.x * 256 + threadIdx.x;
    if (idx < 9 * 64 * 64) {
        int kk = idx >> 12;          // /4096
        int c = (idx >> 6) & 63;
        int cout = idx & 63;
        wT[idx] = weight[(cout * 64 + c) * 9 + kk];
    }
    int j = idx - 9 * 64 * 64;
    if (j >= 0 && j < 64 * 9 * 27) {
        int c = j / 243;
        int k = (j / 27) % 9;
        int ko = j % 27;
        owT[j] = offset_w[(ko * 64 + c) * 9 + k];
    }
}

// ---------------------------------------------------------------------------
// Kernel A: 3x3 conv (C=64 -> 27), pad 1, stride 1. Produces raw offsets
// (channels 0..17) and sigmoid(mask) (channels 18..26).
// One thread = one output pixel, 27 accumulators in registers.
// ---------------------------------------------------------------------------
__global__ __launch_bounds__(256) void offset_conv_kernel(
    const float* __restrict__ x,
    const float* __restrict__ owT,      // (64,9,27)
    const float* __restrict__ offset_b, // (27,)
    float* __restrict__ off_out,        // (B,18,HW)
    float* __restrict__ mask_out)       // (B,9,HW)
{
    int bid = blockIdx.x;
    int b = bid >> 6;                       // 64 blocks per image
    int pix = ((bid & 63) << 8) + threadIdx.x;
    int ho = pix >> 7;
    int wo = pix & 127;

    float acc[27];
#pragma unroll
    for (int ko = 0; ko < 27; ++ko) acc[ko] = offset_b[ko];

    const float* xb = x + (size_t)b * CIN * HW;

    for (int c = 0; c < CIN; ++c) {
        const float* xc = xb + c * HW;
        float v[9];
#pragma unroll
        for (int ky = 0; ky < 3; ++ky) {
            int y = ho + ky - 1;
            bool yok = (unsigned)y < (unsigned)HH;
#pragma unroll
            for (int kx = 0; kx < 3; ++kx) {
                int xx = wo + kx - 1;
                bool ok = yok && ((unsigned)xx < (unsigned)WW);
                v[ky * 3 + kx] = ok ? xc[y * WW + xx] : 0.0f;
            }
        }
        const float* wp = owT + c * 243;  // contiguous, block-uniform
#pragma unroll
        for (int k = 0; k < 9; ++k) {
#pragma unroll
            for (int ko = 0; ko < 27; ++ko) {
                acc[ko] = fmaf(v[k], wp[k * 27 + ko], acc[ko]);
            }
        }
    }

    // channels 0..17 -> offsets; 18..26 -> sigmoid -> mask
#pragma unroll
    for (int j = 0; j < 18; ++j) {
        off_out[((size_t)b * 18 + j) * HW + pix] = acc[j];
    }
#pragma unroll
    for (int kk = 0; kk < 9; ++kk) {
        float a = acc[18 + kk];
        mask_out[((size_t)b * 9 + kk) * HW + pix] = 1.0f / (1.0f + __expf(-a));
    }
}

// ---------------------------------------------------------------------------
// Kernel B: deformable conv. One thread = one output pixel, all 64 Cout
// accumulators in registers. Per (kk): bilinear coords once; per c: 4 gathers
// + bilerp -> s, then 64 FMAs with block-uniform weight reads from wT.
// ---------------------------------------------------------------------------
__global__ __launch_bounds__(256) void deform_kernel(
    const float* __restrict__ x,
    const float* __restrict__ wT,      // (9,64,64) [kk][c][cout]
    const float* __restrict__ bias,    // (64,)
    const float* __restrict__ off_in,  // (B,18,HW)
    const float* __restrict__ mask_in, // (B,9,HW)
    float* __restrict__ out)           // (B,64,HW)
{
    int bid = blockIdx.x;
    int b = bid >> 6;
    int pix = ((bid & 63) << 8) + threadIdx.x;
    int ho = pix >> 7;
    int wo = pix & 127;

    float acc[COUT];
#pragma unroll
    for (int i = 0; i < COUT; ++i) acc[i] = bias[i];

    const float* xb = x + (size_t)b * CIN * HW;

    for (int kk = 0; kk < 9; ++kk) {
        float dy = off_in[((size_t)b * 18 + 2 * kk) * HW + pix];
        float dx = off_in[((size_t)b * 18 + 2 * kk + 1) * HW + pix];
        float m = mask_in[((size_t)b * 9 + kk) * HW + pix];

        int ky = kk / 3;
        int kx = kk - ky * 3;
        float py = dy + (float)(ky + ho - 1);
        float px = dx + (float)(kx + wo - 1);

        float y0f = floorf(py);
        float x0f = floorf(px);
        float wy = py - y0f;
        float wx = px - x0f;
        int y0 = (int)y0f;
        int x0 = (int)x0f;
        int y1 = y0 + 1;
        int x1 = x0 + 1;

        bool y0ok = (unsigned)y0 < (unsigned)HH;
        bool y1ok = (unsigned)y1 < (unsigned)HH;
        bool x0ok = (unsigned)x0 < (unsigned)WW;
        bool x1ok = (unsigned)x1 < (unsigned)WW;

        float w00 = (y0ok && x0ok) ? (1.0f - wy) * (1.0f - wx) * m : 0.0f;
        float w01 = (y0ok && x1ok) ? (1.0f - wy) * wx * m : 0.0f;
        float w10 = (y1ok && x0ok) ? wy * (1.0f - wx) * m : 0.0f;
        float w11 = (y1ok && x1ok) ? wy * wx * m : 0.0f;

        int y0c = min(max(y0, 0), HH - 1);
        int y1c = min(max(y1, 0), HH - 1);
        int x0c = min(max(x0, 0), WW - 1);
        int x1c = min(max(x1, 0), WW - 1);
        int i00 = y0c * WW + x0c;
        int i01 = y0c * WW + x1c;
        int i10 = y1c * WW + x0c;
        int i11 = y1c * WW + x1c;

        const float* wkk = wT + kk * 4096;

        for (int c = 0; c < CIN; ++c) {
            const float* xc = xb + c * HW;
            float s = xc[i00] * w00 + xc[i01] * w01 + xc[i10] * w10 + xc[i11] * w11;
            const float4* wp = (const float4*)(wkk + c * 64);
#pragma unroll
            for (int q = 0; q < 16; ++q) {
                float4 w4 = wp[q];
                acc[q * 4 + 0] = fmaf(s, w4.x, acc[q * 4 + 0]);
                acc[q * 4 + 1] = fmaf(s, w4.y, acc[q * 4 + 1]);
                acc[q * 4 + 2] = fmaf(s, w4.z, acc[q * 4 + 2]);
                acc[q * 4 + 3] = fmaf(s, w4.w, acc[q * 4 + 3]);
            }
        }
    }

    float* ob = out + (size_t)b * COUT * HW + pix;
#pragma unroll
    for (int cout = 0; cout < COUT; ++cout) {
        ob[(size_t)cout * HW] = acc[cout];
    }
}

// ---------------------------------------------------------------------------
extern "C" void kernel_launch(void* const* d_in, const int* in_sizes, int n_in,
                              void* d_out, int out_size, void* d_ws, size_t ws_size,
                              hipStream_t stream) {
    const float* x        = (const float*)d_in[0];
    const float* weight   = (const float*)d_in[1];
    const float* bias     = (const float*)d_in[2];
    const float* offset_w = (const float*)d_in[3];
    const float* offset_b = (const float*)d_in[4];
    float* out = (float*)d_out;

    float* ws = (float*)d_ws;
    float* off_buf  = ws;                            // B*18*HW floats
    float* mask_buf = off_buf + (size_t)BATCH * 18 * HW; // B*9*HW floats
    float* wT       = mask_buf + (size_t)BATCH * 9 * HW; // 9*64*64
    float* owT      = wT + 9 * 64 * 64;                  // 64*9*27

    int n_t = 9 * 64 * 64 + 64 * 9 * 27;
    transpose_kernel<<<(n_t + 255) / 256, 256, 0, stream>>>(weight, offset_w, wT, owT);

    int n_pix_blocks = BATCH * HW / 256;  // 512
    offset_conv_kernel<<<n_pix_blocks, 256, 0, stream>>>(x, owT, offset_b, off_buf, mask_buf);
    deform_kernel<<<n_pix_blocks, 256, 0, stream>>>(x, wT, bias, off_buf, mask_buf, out);
}